// Round 4
// baseline (118.942 us; speedup 1.0000x reference)
//
#include <hip/hip_runtime.h>

// BPNet fused forward: E=16384, ORDER=3, D=13, RANK=128, NUM_PARAMS=4.
// R3: one wave per edge (16384 waves), VGPR<=64 via launch_bounds(256,8)
// for 8 waves/SIMD. Pre-kernel packs W1/bias to bf16 rank-pairs and
// transposes W2 to [i][ty][d][r] in d_ws. Stage 2: facts via padded LDS
// (conflict-free), 8 x (b128 LDS + dwordx4 global) + 32 FMA + 2 shfl_xor.
// NUM_ITERS loop in reference is idempotent -> one iteration.

#define DD 13
#define RK 128
#define OD 3
#define NP 4

// ws layout (dword offsets)
#define W2T_OFF 0        // [12][16][128] f32 (rows d=13..15 zeroed)
#define W1P_OFF 24576    // [4][13][64] packed bf16 pairs (ranks 2l, 2l+1)
#define B1P_OFF 27904    // [4][64] packed bf16 pairs
#define PRE_TOT 28160

#define FSTR 36          // padded per-g-group stride (dwords)
#define FSLOT (4 * FSTR) // 144 dwords per slot

typedef float f4 __attribute__((ext_vector_type(4)));
typedef float f2 __attribute__((ext_vector_type(2)));

__device__ __forceinline__ unsigned bf16pair(float lo, float hi) {
    unsigned ul = __float_as_uint(lo);
    unsigned uh = __float_as_uint(hi);
    ul += 0x7fffu + ((ul >> 16) & 1u);   // RNE to bf16
    uh += 0x7fffu + ((uh >> 16) & 1u);
    return (ul >> 16) | (uh & 0xffff0000u);
}
__device__ __forceinline__ float bflo(unsigned w) { return __uint_as_float(w << 16); }
__device__ __forceinline__ float bfhi(unsigned w) { return __uint_as_float(w & 0xffff0000u); }

__global__ __launch_bounds__(256) void bpnet_pack(
    const float* __restrict__ bp_params,  // [4,13,128]
    const float* __restrict__ bp_bias,    // [4,1,128]
    const float* __restrict__ ho_params,  // [3,4,128,13]
    float* __restrict__ ws)
{
    const int tid = blockIdx.x * 256 + threadIdx.x;
    if (tid < 24576) {
        const int r = tid & 127, d = (tid >> 7) & 15, it = tid >> 11;  // it=i*4+ty
        float v = (d < DD) ? ho_params[(size_t)(it * RK + r) * DD + d] : 0.f;
        ws[W2T_OFF + tid] = v;
    } else if (tid < W1P_OFF + 3328) {
        const int j = tid - W1P_OFF;
        const int l = j & 63, dt = j >> 6;  // dt = ty*13+d
        ((unsigned*)ws)[W1P_OFF + j] =
            bf16pair(bp_params[dt * RK + 2 * l], bp_params[dt * RK + 2 * l + 1]);
    } else if (tid < PRE_TOT) {
        const int j = tid - B1P_OFF;
        const int l = j & 63, ty = j >> 6;
        ((unsigned*)ws)[B1P_OFF + j] =
            bf16pair(bp_bias[ty * RK + 2 * l], bp_bias[ty * RK + 2 * l + 1]);
    }
}

__global__ __launch_bounds__(256, 8) void bpnet_fused(
    const float* __restrict__ nodes,      // [N, 13]
    const float* __restrict__ ho_bias,    // [3,4,1,13]
    const int*   __restrict__ edges,      // [E, 3]
    const int*   __restrict__ edge_types, // [E, 3]
    const float* __restrict__ w2t,        // [12][16][128]
    const unsigned* __restrict__ w1p,     // [4][13][64]
    const unsigned* __restrict__ b1p,     // [4][64]
    float*       __restrict__ out)        // [N, 13] (pre-zeroed)
{
    __shared__ float fact_lds[4][OD * FSLOT];  // 6912 B
    const int lane = threadIdx.x & 63;
    const int wv   = threadIdx.x >> 6;
    const int e    = blockIdx.x * 4 + wv;

    int et[OD], tg[OD];
#pragma unroll
    for (int o = 0; o < OD; ++o) {
        et[o] = __builtin_amdgcn_readfirstlane(edge_types[e * OD + o]);
        tg[o] = __builtin_amdgcn_readfirstlane(edges[e * OD + o]);
    }

    // ---- stage 1: lane owns ranks {2*lane, 2*lane+1} ----
    float t0[OD], t1[OD];
#pragma unroll
    for (int o = 0; o < OD; ++o) {
        const float* nr = nodes + (size_t)tg[o] * DD;  // uniform -> s_load
        float nv[DD];
#pragma unroll
        for (int d = 0; d < DD; ++d) nv[d] = nr[d];
        const unsigned* wp = w1p + et[o] * DD * 64 + lane;
        const unsigned bw = b1p[et[o] * 64 + lane];
        float s0 = bflo(bw), s1 = bfhi(bw);
#pragma unroll
        for (int d = 0; d < DD; ++d) {
            const unsigned w = wp[d * 64];
            s0 = fmaf(nv[d], bflo(w), s0);
            s1 = fmaf(nv[d], bfhi(w), s1);
        }
        t0[o] = fmaxf(s0, 0.f);
        t1[o] = fmaxf(s1, 0.f);
    }

    // ---- facts -> LDS (rank order, per-g padded stride 36) ----
    float* myf = fact_lds[wv];
    const int fw = (lane >> 4) * FSTR + 2 * (lane & 15);  // 8B aligned
#pragma unroll
    for (int i = 0; i < OD; ++i) {
        const int j = (i + 1) % OD, k = (i + 2) % OD;
        f2 v;
        v.x = t0[j] * t0[k];   // rank 2*lane
        v.y = t1[j] * t1[k];   // rank 2*lane+1
        *(f2*)(myf + i * FSLOT + fw) = v;
    }
    // same-wave LDS RAW -> compiler inserts lgkmcnt wait; no barrier needed

    // ---- stage 2: lane (g, d) sums ranks [g*32, g*32+32) for dim d ----
    const int g = lane >> 4;
    const int dsel = lane & 15;
    const int dd = (dsel < DD) ? dsel : 0;
#pragma unroll
    for (int i = 0; i < OD; ++i) {
        const float* wb = w2t + (size_t)((i * NP + et[i]) * 16 + dd) * RK + g * 32;
        const float* fp = myf + i * FSLOT + g * FSTR;
        f4 acc = {0.f, 0.f, 0.f, 0.f};
#pragma unroll
        for (int c = 0; c < 8; ++c) {
            const f4 w = *(const f4*)(wb + c * 4);
            const f4 f = *(const f4*)(fp + c * 4);   // ds_read_b128, conflict-free
            acc.x = fmaf(w.x, f.x, acc.x);
            acc.y = fmaf(w.y, f.y, acc.y);
            acc.z = fmaf(w.z, f.z, acc.z);
            acc.w = fmaf(w.w, f.w, acc.w);
        }
        float q = (acc.x + acc.y) + (acc.z + acc.w);
        q += __shfl_xor(q, 16, 64);   // combine g pairs
        q += __shfl_xor(q, 32, 64);   // combine halves
        if (lane < DD) {
            q += ho_bias[(i * NP + et[i]) * DD + lane];
            atomicAdd(out + (size_t)tg[i] * DD + lane, q);
        }
    }
}

extern "C" void kernel_launch(void* const* d_in, const int* in_sizes, int n_in,
                              void* d_out, int out_size, void* d_ws, size_t ws_size,
                              hipStream_t stream) {
    const float* nodes      = (const float*)d_in[0];
    const float* bp_params  = (const float*)d_in[1];
    const float* bp_bias    = (const float*)d_in[2];
    const float* ho_params  = (const float*)d_in[3];
    const float* ho_bias    = (const float*)d_in[4];
    const int*   edges      = (const int*)d_in[5];
    const int*   edge_types = (const int*)d_in[6];
    float* out = (float*)d_out;
    float* ws  = (float*)d_ws;

    const int E = in_sizes[5] / OD;

    // out is poisoned 0xAA before every timed call — zero it for the atomics.
    hipMemsetAsync(out, 0, (size_t)out_size * sizeof(float), stream);

    bpnet_pack<<<(PRE_TOT + 255) / 256, 256, 0, stream>>>(
        bp_params, bp_bias, ho_params, ws);

    bpnet_fused<<<E / 4, 256, 0, stream>>>(
        nodes, ho_bias, edges, edge_types,
        ws + W2T_OFF, (const unsigned*)ws + W1P_OFF, (const unsigned*)ws + B1P_OFF,
        out);
}

// Round 5
// 87.851 us; speedup vs baseline: 1.3539x; 1.3539x over previous
//
#include <hip/hip_runtime.h>

// BPNet fused forward: E=16384, ORDER=3, D=13, RANK=128, NUM_PARAMS=4.
// R4: ALL weight tables live in LDS (bf16 rank-pairs, stride-68 padded rows,
// 64.5 KB/block). Lane (e4 = lane>>4, g = lane&15) owns ranks 8g..8g+7 of
// edge e4 in BOTH stages -> facts stay in registers (no LDS round-trip).
// Node rows cooperatively gathered into LDS per wave. Reduction: 4 DPP
// row-sum16 + cndmask select + 1 atomic per edge-slot.
// NUM_ITERS loop in reference is idempotent -> one iteration.

#define DD 13
#define OD 3
#define NP 4
#define RK 128

typedef unsigned int uint;

// packed table layout (uint offsets) in ws and LDS
#define W2P_OFF 0                  // [12][13][68] bf16 pairs (ranks 2c,2c+1)
#define W2P_N   (12 * 13 * 68)     // 10608
#define W1P_OFF (W2P_OFF + W2P_N)  // [4][13][68]
#define W1P_N   (4 * 13 * 68)      // 3536
#define B1Q_OFF (W1P_OFF + W1P_N)  // [4][68]
#define B1Q_N   (4 * 68)           // 272
#define HOB_OFF (B1Q_OFF + B1Q_N)  // [12][16] f32
#define HOB_N   (12 * 16)          // 192
#define TAB_N   (HOB_OFF + HOB_N)  // 14608 uints = 58432 B
#define NROW_N  (4 * 24 * 16)      // per-wave node rows, f32
#define SH_N    (TAB_N + NROW_N)   // 16144 uints = 64576 B

__device__ __forceinline__ uint bf16pair(float lo, float hi) {
    uint ul = __float_as_uint(lo);
    uint uh = __float_as_uint(hi);
    ul += 0x7fffu + ((ul >> 16) & 1u);   // RNE to bf16
    uh += 0x7fffu + ((uh >> 16) & 1u);
    return (ul >> 16) | (uh & 0xffff0000u);
}
__device__ __forceinline__ float bflo(uint w) { return __uint_as_float(w << 16); }
__device__ __forceinline__ float bfhi(uint w) { return __uint_as_float(w & 0xffff0000u); }

template <int CTRL>
__device__ __forceinline__ float dpp_add(float x) {
    int p = __builtin_amdgcn_update_dpp(0, __float_as_int(x), CTRL, 0xF, 0xF, false);
    return x + __int_as_float(p);
}
__device__ __forceinline__ float row_sum16(float x) {
    x = dpp_add<0xB1>(x);   // quad_perm xor1
    x = dpp_add<0x4E>(x);   // quad_perm xor2
    x = dpp_add<0x141>(x);  // row_half_mirror
    x = dpp_add<0x140>(x);  // row_mirror -> every lane has its row-of-16 sum
    return x;
}

__global__ __launch_bounds__(256) void bpnet_pack(
    const float* __restrict__ bp_params,  // [4,13,128]
    const float* __restrict__ bp_bias,    // [4,1,128]
    const float* __restrict__ ho_params,  // [3,4,128,13]
    const float* __restrict__ ho_bias,    // [3,4,1,13]
    uint* __restrict__ ws)
{
    const int tid = blockIdx.x * 256 + threadIdx.x;
    if (tid < W1P_OFF) {                       // w2p: [it][dd][c]
        const int c = tid % 68, q = tid / 68;
        const int dd = q % 13, it = q / 13;
        uint v = 0;
        if (c < 64)
            v = bf16pair(ho_params[(size_t)(it * RK + 2 * c) * DD + dd],
                         ho_params[(size_t)(it * RK + 2 * c + 1) * DD + dd]);
        ws[tid] = v;
    } else if (tid < B1Q_OFF) {                // w1p: [ty][d][c]
        const int j = tid - W1P_OFF;
        const int c = j % 68, q = j / 68;
        const int d = q % 13, ty = q / 13;
        uint v = 0;
        if (c < 64)
            v = bf16pair(bp_params[(ty * DD + d) * RK + 2 * c],
                         bp_params[(ty * DD + d) * RK + 2 * c + 1]);
        ws[tid] = v;
    } else if (tid < HOB_OFF) {                // b1q: [ty][c]
        const int j = tid - B1Q_OFF;
        const int c = j % 68, ty = j / 68;
        uint v = 0;
        if (c < 64)
            v = bf16pair(bp_bias[ty * RK + 2 * c], bp_bias[ty * RK + 2 * c + 1]);
        ws[tid] = v;
    } else if (tid < TAB_N) {                  // hob: [it][16] f32
        const int j = tid - HOB_OFF;
        const int dd = j % 16, it = j / 16;
        ((float*)ws)[tid] = (dd < DD) ? ho_bias[it * DD + dd] : 0.f;
    }
}

__global__ __launch_bounds__(256, 2) void bpnet_fused(
    const float* __restrict__ nodes,      // [N, 13]
    const int*   __restrict__ edges,      // [E, 3]
    const int*   __restrict__ edge_types, // [E, 3]
    const uint*  __restrict__ tab,        // packed tables (TAB_N uints)
    float*       __restrict__ out)        // [N, 13] (pre-zeroed)
{
    __shared__ __align__(16) uint sh[SH_N];
    const int tid = threadIdx.x;

    // ---- stage tables into LDS (one flat uint4 copy) ----
    for (int k4 = tid; k4 < TAB_N / 4; k4 += 256)
        ((uint4*)sh)[k4] = ((const uint4*)tab)[k4];
    __syncthreads();

    const uint*  w2p = sh + W2P_OFF;
    const uint*  w1p = sh + W1P_OFF;
    const uint*  b1q = sh + B1Q_OFF;
    const float* hob = (const float*)(sh + HOB_OFF);
    float* nrow = (float*)(sh + TAB_N);

    const int lane = tid & 63;
    const int wv   = tid >> 6;
    const int e4   = lane >> 4;   // edge within chunk of 4
    const int g    = lane & 15;   // rank octet: ranks 8g..8g+7
    const int eb   = (blockIdx.x * 4 + wv) * 8;   // 8 edges per wave

    // ---- wave metadata: 24 ints each (8 edges x 3 slots) ----
    int ev = 0, tv = 0;
    if (lane < 24) {
        ev = edges[eb * OD + lane];
        tv = edge_types[eb * OD + lane];
    }
    // ---- gather 24 node rows (13 f32 each) into LDS ----
    float* mynr = nrow + wv * (24 * 16);
#pragma unroll
    for (int c = 0; c < 5; ++c) {
        const int idx = c * 64 + lane;
        if (idx < 312) {
            const int r = idx / 13, col = idx - r * 13;
            const int nr_ = __shfl(ev, r, 64);
            mynr[r * 16 + col] = nodes[(size_t)nr_ * DD + col];
        }
    }
    // same-wave LDS write->read: in-order per wave, compiler inserts waits

#pragma unroll 1
    for (int ch = 0; ch < 2; ++ch) {
        int tg[OD], et[OD];
#pragma unroll
        for (int i = 0; i < OD; ++i) {
            tg[i] = __shfl(ev, ch * 12 + e4 * 3 + i, 64);
            et[i] = __shfl(tv, ch * 12 + e4 * 3 + i, 64);
        }

        // ---- stage 1: t[o][0..7] for ranks 8g..8g+7 of edge e4 ----
        float t[OD][8];
#pragma unroll
        for (int o = 0; o < OD; ++o) {
            const float* nr_ = mynr + (ch * 12 + e4 * 3 + o) * 16;
            const float4 nA = *(const float4*)(nr_);
            const float4 nB = *(const float4*)(nr_ + 4);
            const float4 nC = *(const float4*)(nr_ + 8);
            const float  nD = nr_[12];
            const uint* wq = w1p + (et[o] * 13) * 68 + 4 * g;
            const uint4 bq = *(const uint4*)(b1q + et[o] * 68 + 4 * g);
            float s[8] = {bflo(bq.x), bfhi(bq.x), bflo(bq.y), bfhi(bq.y),
                          bflo(bq.z), bfhi(bq.z), bflo(bq.w), bfhi(bq.w)};
#define S1(dn, nv_) { const uint4 w = *(const uint4*)(wq + (dn) * 68);       \
            s[0] = fmaf(nv_, bflo(w.x), s[0]); s[1] = fmaf(nv_, bfhi(w.x), s[1]); \
            s[2] = fmaf(nv_, bflo(w.y), s[2]); s[3] = fmaf(nv_, bfhi(w.y), s[3]); \
            s[4] = fmaf(nv_, bflo(w.z), s[4]); s[5] = fmaf(nv_, bfhi(w.z), s[5]); \
            s[6] = fmaf(nv_, bflo(w.w), s[6]); s[7] = fmaf(nv_, bfhi(w.w), s[7]); }
            S1(0, nA.x) S1(1, nA.y) S1(2, nA.z) S1(3, nA.w)
            S1(4, nB.x) S1(5, nB.y) S1(6, nB.z) S1(7, nB.w)
            S1(8, nC.x) S1(9, nC.y) S1(10, nC.z) S1(11, nC.w)
            S1(12, nD)
#undef S1
#pragma unroll
            for (int r = 0; r < 8; ++r) t[o][r] = fmaxf(s[r], 0.f);
        }

        // ---- stage 2: facts in registers, weights from LDS ----
#pragma unroll
        for (int i = 0; i < OD; ++i) {
            const int j = (i + 1) % OD, k = (i + 2) % OD;
            float f[8];
#pragma unroll
            for (int r = 0; r < 8; ++r) f[r] = t[j][r] * t[k][r];
            const int it = i * NP + et[i];
            const uint* wq2 = w2p + (it * 13) * 68 + 4 * g;
            float c[DD];
#pragma unroll
            for (int dd = 0; dd < DD; ++dd) {
                const uint4 w = *(const uint4*)(wq2 + dd * 68);
                float a = f[0] * bflo(w.x);
                a = fmaf(f[1], bfhi(w.x), a);
                a = fmaf(f[2], bflo(w.y), a);
                a = fmaf(f[3], bfhi(w.y), a);
                a = fmaf(f[4], bflo(w.z), a);
                a = fmaf(f[5], bfhi(w.z), a);
                a = fmaf(f[6], bflo(w.w), a);
                a = fmaf(f[7], bfhi(w.w), a);
                c[dd] = a;
            }
#pragma unroll
            for (int dd = 0; dd < DD; ++dd) c[dd] = row_sum16(c[dd]);
            float q = c[0];
#pragma unroll
            for (int dd = 1; dd < DD; ++dd) q = (g == dd) ? c[dd] : q;
            q += hob[it * 16 + g];
            if (g < DD) atomicAdd(out + (size_t)tg[i] * DD + g, q);
        }
    }
}

extern "C" void kernel_launch(void* const* d_in, const int* in_sizes, int n_in,
                              void* d_out, int out_size, void* d_ws, size_t ws_size,
                              hipStream_t stream) {
    const float* nodes      = (const float*)d_in[0];
    const float* bp_params  = (const float*)d_in[1];
    const float* bp_bias    = (const float*)d_in[2];
    const float* ho_params  = (const float*)d_in[3];
    const float* ho_bias    = (const float*)d_in[4];
    const int*   edges      = (const int*)d_in[5];
    const int*   edge_types = (const int*)d_in[6];
    float* out = (float*)d_out;
    uint*  ws  = (uint*)d_ws;

    const int E = in_sizes[5] / OD;   // 16384

    // out is poisoned 0xAA before every timed call — zero it for the atomics.
    hipMemsetAsync(out, 0, (size_t)out_size * sizeof(float), stream);

    bpnet_pack<<<(TAB_N + 255) / 256, 256, 0, stream>>>(
        bp_params, bp_bias, ho_params, ho_bias, ws);

    // 512 blocks x 4 waves x 8 edges = 16384
    bpnet_fused<<<E / 32, 256, 0, stream>>>(
        nodes, edges, edge_types, ws, out);
}

// Round 7
// 82.871 us; speedup vs baseline: 1.4353x; 1.0601x over previous
//
#include <hip/hip_runtime.h>

// BPNet fused forward: E=16384, ORDER=3, D=13, RANK=128, NUM_PARAMS=4.
// R6 = R5 with compile fix (cvt_pkrtz returns __fp16 vector; bit_cast it).
// Tables packed to f16 (v_dot2_f32_f16: 2 MACs/inst, f32 accumulate),
// 512-thread blocks (8 waves) x 4 edges/wave -> 2 blocks/CU, 16 waves/CU.
// Lane (e4 = lane>>4, g = lane&15) owns ranks 8g..8g+7 of edge e4 in both
// stages; facts stay in registers. Reduction: 4 DPP row_sum16 + select.
// NUM_ITERS loop in reference is idempotent -> one iteration.

#define DD 13
#define OD 3
#define NP 4
#define RK 128

typedef unsigned int uint;
typedef _Float16 h2 __attribute__((ext_vector_type(2)));

// LDS/ws layout (dword offsets)
#define W2H_OFF 0                    // [12][13][64] h2: (ranks 2c,2c+1) for dim dd
#define W2H_N   (12 * 13 * 64)       // 9984
#define W1H_OFF (W2H_OFF + W2H_N)    // [4][7][128] h2: (d=2p, d=2p+1) for rank r
#define W1H_N   (4 * 7 * 128)        // 3584
#define B1F_OFF (W1H_OFF + W1H_N)    // [4][128] f32 bias
#define B1F_N   (4 * 128)            // 512
#define HOB_OFF (B1F_OFF + B1F_N)    // [12][16] f32 (dd>=13 zeroed)
#define HOB_N   (12 * 16)            // 192
#define TAB_N   (HOB_OFF + HOB_N)    // 14272 dwords = 57088 B
#define NROW_OFF TAB_N               // [8 waves][12 rows][8] h2 node d-pairs
#define NROW_N  (8 * 12 * 8)         // 768
#define SH_N    (TAB_N + NROW_N)     // 15040 dwords = 60160 B

__device__ __forceinline__ uint pk(float lo, float hi) {
    return __builtin_bit_cast(uint, __builtin_amdgcn_cvt_pkrtz(lo, hi));
}
__device__ __forceinline__ h2 ash2(uint w) { return __builtin_bit_cast(h2, w); }

template <int CTRL>
__device__ __forceinline__ float dpp_add(float x) {
    int p = __builtin_amdgcn_update_dpp(0, __float_as_int(x), CTRL, 0xF, 0xF, false);
    return x + __int_as_float(p);
}
__device__ __forceinline__ float row_sum16(float x) {
    x = dpp_add<0xB1>(x);   // quad_perm xor1
    x = dpp_add<0x4E>(x);   // quad_perm xor2
    x = dpp_add<0x141>(x);  // row_half_mirror
    x = dpp_add<0x140>(x);  // row_mirror -> lane has its row-of-16 sum
    return x;
}

__global__ __launch_bounds__(256) void bpnet_pack(
    const float* __restrict__ bp_params,  // [4,13,128]
    const float* __restrict__ bp_bias,    // [4,1,128]
    const float* __restrict__ ho_params,  // [3,4,128,13]
    const float* __restrict__ ho_bias,    // [3,4,1,13]
    uint* __restrict__ ws)
{
    const int tid = blockIdx.x * 256 + threadIdx.x;
    if (tid < W1H_OFF) {                       // W2H [it][dd][c]
        const int c = tid & 63, q = tid >> 6;
        const int dd = q % 13, it = q / 13;
        ws[tid] = pk(ho_params[(size_t)(it * RK + 2 * c) * DD + dd],
                     ho_params[(size_t)(it * RK + 2 * c + 1) * DD + dd]);
    } else if (tid < B1F_OFF) {                // W1H [ty][p][r]
        const int j = tid - W1H_OFF;
        const int r = j & 127, q = j >> 7;
        const int p = q % 7, ty = q / 7;
        const float a = bp_params[(ty * DD + 2 * p) * RK + r];
        const float b = (2 * p + 1 < DD) ? bp_params[(ty * DD + 2 * p + 1) * RK + r] : 0.f;
        ws[tid] = pk(a, b);
    } else if (tid < HOB_OFF) {                // B1F f32 copy
        ((float*)ws)[tid] = bp_bias[tid - B1F_OFF];
    } else if (tid < TAB_N) {                  // HOB [it][16]
        const int j = tid - HOB_OFF;
        const int dd = j & 15, it = j >> 4;
        ((float*)ws)[tid] = (dd < DD) ? ho_bias[it * DD + dd] : 0.f;
    }
}

__global__ __launch_bounds__(512, 4) void bpnet_fused(
    const float* __restrict__ nodes,      // [N, 13]
    const int*   __restrict__ edges,      // [E, 3]
    const int*   __restrict__ edge_types, // [E, 3]
    const uint*  __restrict__ tab,        // packed tables (TAB_N dwords)
    float*       __restrict__ out)        // [N, 13] (pre-zeroed)
{
    __shared__ __align__(16) uint sh[SH_N];
    const int tid = threadIdx.x;

    // ---- stage packed tables into LDS (flat uint4 copy) ----
    for (int k4 = tid; k4 < TAB_N / 4; k4 += 512)
        ((uint4*)sh)[k4] = ((const uint4*)tab)[k4];
    __syncthreads();

    const int lane = tid & 63;
    const int wv   = tid >> 6;        // 0..7
    const int e4   = lane >> 4;       // edge within wave's 4
    const int g    = lane & 15;       // rank octet 8g..8g+7
    const int eb   = (blockIdx.x * 8 + wv) * 4;

    // ---- wave metadata: 12 ints each ----
    int ev = 0, tv = 0;
    if (lane < 12) {
        ev = edges[eb * OD + lane];
        tv = edge_types[eb * OD + lane];
    }

    // ---- gather 12 node rows as packed h2 d-pairs into LDS ----
    uint* mynr = sh + NROW_OFF + wv * 96;
#pragma unroll
    for (int pass = 0; pass < 2; ++pass) {
        const int idx = pass * 64 + lane;
        if (idx < 96) {
            const int r = idx >> 3, p = idx & 7;
            const int nr_ = __shfl(ev, r, 64);
            uint v = 0;
            if (p < 6)       v = pk(nodes[(size_t)nr_ * DD + 2 * p],
                                    nodes[(size_t)nr_ * DD + 2 * p + 1]);
            else if (p == 6) v = pk(nodes[(size_t)nr_ * DD + 12], 0.f);
            mynr[r * 8 + p] = v;
        }
    }
    // same-wave LDS write->read: in-order, compiler inserts lgkmcnt waits

    int tg[OD], et[OD];
#pragma unroll
    for (int i = 0; i < OD; ++i) {
        tg[i] = __shfl(ev, e4 * OD + i, 64);
        et[i] = __shfl(tv, e4 * OD + i, 64);
    }

    // ---- stage 1: t[o][0..7] for ranks 8g..8g+7 of edge e4 ----
    float t[OD][8];
#pragma unroll
    for (int o = 0; o < OD; ++o) {
        const uint* nh = mynr + (e4 * OD + o) * 8;
        const uint4 n0 = *(const uint4*)(nh);       // d-pairs 0..3 (broadcast)
        const uint4 n1 = *(const uint4*)(nh + 4);   // d-pairs 4..6 (+pad)
        const float* bf = (const float*)(sh + B1F_OFF) + et[o] * RK + 8 * g;
        const float4 b0 = *(const float4*)(bf);
        const float4 b1 = *(const float4*)(bf + 4);
        float s[8] = {b0.x, b0.y, b0.z, b0.w, b1.x, b1.y, b1.z, b1.w};
        const uint* wb = sh + W1H_OFF + (et[o] * 7) * RK + 8 * g;
#define S1(p, nv) { const uint4 wA = *(const uint4*)(wb + (p) * RK);          \
                    const uint4 wB = *(const uint4*)(wb + (p) * RK + 4);      \
            const h2 nn = ash2(nv);                                           \
            s[0] = __builtin_amdgcn_fdot2(nn, ash2(wA.x), s[0], false);       \
            s[1] = __builtin_amdgcn_fdot2(nn, ash2(wA.y), s[1], false);       \
            s[2] = __builtin_amdgcn_fdot2(nn, ash2(wA.z), s[2], false);       \
            s[3] = __builtin_amdgcn_fdot2(nn, ash2(wA.w), s[3], false);       \
            s[4] = __builtin_amdgcn_fdot2(nn, ash2(wB.x), s[4], false);       \
            s[5] = __builtin_amdgcn_fdot2(nn, ash2(wB.y), s[5], false);       \
            s[6] = __builtin_amdgcn_fdot2(nn, ash2(wB.z), s[6], false);       \
            s[7] = __builtin_amdgcn_fdot2(nn, ash2(wB.w), s[7], false); }
        S1(0, n0.x) S1(1, n0.y) S1(2, n0.z) S1(3, n0.w)
        S1(4, n1.x) S1(5, n1.y) S1(6, n1.z)
#undef S1
#pragma unroll
        for (int r = 0; r < 8; ++r) t[o][r] = fmaxf(s[r], 0.f);
    }

    // ---- stage 2: facts in registers -> h2, dot2 vs W2H rows ----
#pragma unroll
    for (int i = 0; i < OD; ++i) {
        const int j = (i + 1) % OD, k = (i + 2) % OD;
        uint fh[4];
#pragma unroll
        for (int r = 0; r < 4; ++r)
            fh[r] = pk(t[j][2 * r] * t[k][2 * r], t[j][2 * r + 1] * t[k][2 * r + 1]);
        const int it = i * NP + et[i];
        const uint* wb = sh + W2H_OFF + (it * DD) * 64 + 4 * g;
        float c[DD];
#pragma unroll
        for (int dd = 0; dd < DD; ++dd) {
            const uint4 w = *(const uint4*)(wb + dd * 64);
            float a = __builtin_amdgcn_fdot2(ash2(fh[0]), ash2(w.x), 0.f, false);
            a = __builtin_amdgcn_fdot2(ash2(fh[1]), ash2(w.y), a, false);
            a = __builtin_amdgcn_fdot2(ash2(fh[2]), ash2(w.z), a, false);
            a = __builtin_amdgcn_fdot2(ash2(fh[3]), ash2(w.w), a, false);
            c[dd] = a;
        }
#pragma unroll
        for (int dd = 0; dd < DD; ++dd) c[dd] = row_sum16(c[dd]);
        float q = c[0];
#pragma unroll
        for (int dd = 1; dd < DD; ++dd) q = (g == dd) ? c[dd] : q;
        q += ((const float*)(sh + HOB_OFF))[it * 16 + g];
        if (g < DD) atomicAdd(out + (size_t)tg[i] * DD + g, q);
    }
}

extern "C" void kernel_launch(void* const* d_in, const int* in_sizes, int n_in,
                              void* d_out, int out_size, void* d_ws, size_t ws_size,
                              hipStream_t stream) {
    const float* nodes      = (const float*)d_in[0];
    const float* bp_params  = (const float*)d_in[1];
    const float* bp_bias    = (const float*)d_in[2];
    const float* ho_params  = (const float*)d_in[3];
    const float* ho_bias    = (const float*)d_in[4];
    const int*   edges      = (const int*)d_in[5];
    const int*   edge_types = (const int*)d_in[6];
    float* out = (float*)d_out;
    uint*  ws  = (uint*)d_ws;

    const int E = in_sizes[5] / OD;   // 16384

    // out is poisoned 0xAA before every timed call — zero it for the atomics.
    (void)hipMemsetAsync(out, 0, (size_t)out_size * sizeof(float), stream);

    bpnet_pack<<<(TAB_N + 255) / 256, 256, 0, stream>>>(
        bp_params, bp_bias, ho_params, ho_bias, ws);

    // E/32 = 512 blocks x 8 waves x 4 edges = 16384
    bpnet_fused<<<E / 32, 512, 0, stream>>>(nodes, edges, edge_types, ws, out);
}

// Round 8
// 80.923 us; speedup vs baseline: 1.4698x; 1.0241x over previous
//
#include <hip/hip_runtime.h>

// BPNet fused forward: E=16384, ORDER=3, D=13, RANK=128, NUM_PARAMS=4.
// R7 = R6 + (1) stage-1 LDS tables split A/B so lane reads 4g..4g+3
// (all 32 banks, 2-way = free) instead of 8g stride (16 banks, 2x conflict);
// (2) out-zeroing folded into pack kernel (one fewer dispatch);
// (3) node gather hoisted above table staging to overlap global latency.
// Tables f16-packed (v_dot2_f32_f16), 512-thread blocks x 4 edges/wave,
// 2 blocks/CU resident, facts stay in registers, DPP row_sum16 reduction.
// NUM_ITERS loop in reference is idempotent -> one iteration.

#define DD 13
#define OD 3
#define NP 4
#define RK 128

typedef unsigned int uint;
typedef _Float16 h2 __attribute__((ext_vector_type(2)));

// LDS/ws layout (dword offsets)
#define W2H_OFF 0                    // [12][13][64] h2: dword c -> ranks (2c,2c+1), dim dd
#define W2H_N   (12 * 13 * 64)       // 9984
#define W1A_OFF (W2H_OFF + W2H_N)    // [4][7][64] h2: c=4g+k -> rank 8g+k, d-pair p
#define W1A_N   (4 * 7 * 64)         // 1792
#define W1B_OFF (W1A_OFF + W1A_N)    // [4][7][64]: rank 8g+4+k
#define W1B_N   (4 * 7 * 64)         // 1792
#define B1A_OFF (W1B_OFF + W1B_N)    // [4][64] f32: c=4g+k -> bias rank 8g+k
#define B1A_N   (4 * 64)             // 256
#define B1B_OFF (B1A_OFF + B1A_N)    // [4][64] f32: rank 8g+4+k
#define B1B_N   (4 * 64)             // 256
#define HOB_OFF (B1B_OFF + B1B_N)    // [12][16] f32 (dd>=13 zeroed)
#define HOB_N   (12 * 16)            // 192
#define TAB_N   (HOB_OFF + HOB_N)    // 14272 dwords = 57088 B
#define NROW_OFF TAB_N               // [8 waves][12 rows][8] h2 node d-pairs
#define NROW_N  (8 * 12 * 8)         // 768
#define SH_N    (TAB_N + NROW_N)     // 15040 dwords = 60160 B

__device__ __forceinline__ uint pk(float lo, float hi) {
    return __builtin_bit_cast(uint, __builtin_amdgcn_cvt_pkrtz(lo, hi));
}
__device__ __forceinline__ h2 ash2(uint w) { return __builtin_bit_cast(h2, w); }

template <int CTRL>
__device__ __forceinline__ float dpp_add(float x) {
    int p = __builtin_amdgcn_update_dpp(0, __float_as_int(x), CTRL, 0xF, 0xF, false);
    return x + __int_as_float(p);
}
__device__ __forceinline__ float row_sum16(float x) {
    x = dpp_add<0xB1>(x);   // quad_perm xor1
    x = dpp_add<0x4E>(x);   // quad_perm xor2
    x = dpp_add<0x141>(x);  // row_half_mirror
    x = dpp_add<0x140>(x);  // row_mirror -> lane has its row-of-16 sum
    return x;
}

__global__ __launch_bounds__(256) void bpnet_pack(
    const float* __restrict__ bp_params,  // [4,13,128]
    const float* __restrict__ bp_bias,    // [4,1,128]
    const float* __restrict__ ho_params,  // [3,4,128,13]
    const float* __restrict__ ho_bias,    // [3,4,1,13]
    uint* __restrict__ ws,
    uint* __restrict__ outz, int out_n)   // also zero the output buffer
{
    const int tid = blockIdx.x * 256 + threadIdx.x;
    const int nthr = gridDim.x * 256;

    // ---- zero out (grid-stride uint4) ----
    const int n4 = out_n >> 2;
    for (int k = tid; k < n4; k += nthr) ((uint4*)outz)[k] = uint4{0, 0, 0, 0};
    if (tid < (out_n & 3)) outz[(n4 << 2) + tid] = 0;

    // ---- pack tables ----
    if (tid < W1A_OFF) {                       // W2H [it][dd][c]
        const int c = tid & 63, q = tid >> 6;
        const int dd = q % 13, it = q / 13;
        ws[tid] = pk(ho_params[(size_t)(it * RK + 2 * c) * DD + dd],
                     ho_params[(size_t)(it * RK + 2 * c + 1) * DD + dd]);
    } else if (tid < W1B_OFF) {                // W1A [ty][p][c], rank 8g+k
        const int j = tid - W1A_OFF;
        const int c = j & 63, q = j >> 6;
        const int p = q % 7, ty = q / 7;
        const int r = 8 * (c >> 2) + (c & 3);
        const float a = bp_params[(ty * DD + 2 * p) * RK + r];
        const float b = (2 * p + 1 < DD) ? bp_params[(ty * DD + 2 * p + 1) * RK + r] : 0.f;
        ws[tid] = pk(a, b);
    } else if (tid < B1A_OFF) {                // W1B [ty][p][c], rank 8g+4+k
        const int j = tid - W1B_OFF;
        const int c = j & 63, q = j >> 6;
        const int p = q % 7, ty = q / 7;
        const int r = 8 * (c >> 2) + 4 + (c & 3);
        const float a = bp_params[(ty * DD + 2 * p) * RK + r];
        const float b = (2 * p + 1 < DD) ? bp_params[(ty * DD + 2 * p + 1) * RK + r] : 0.f;
        ws[tid] = pk(a, b);
    } else if (tid < B1B_OFF) {                // B1A f32
        const int j = tid - B1A_OFF;
        const int c = j & 63, ty = j >> 6;
        ((float*)ws)[tid] = bp_bias[ty * RK + 8 * (c >> 2) + (c & 3)];
    } else if (tid < HOB_OFF) {                // B1B f32
        const int j = tid - B1B_OFF;
        const int c = j & 63, ty = j >> 6;
        ((float*)ws)[tid] = bp_bias[ty * RK + 8 * (c >> 2) + 4 + (c & 3)];
    } else if (tid < TAB_N) {                  // HOB [it][16]
        const int j = tid - HOB_OFF;
        const int dd = j & 15, it = j >> 4;
        ((float*)ws)[tid] = (dd < DD) ? ho_bias[it * DD + dd] : 0.f;
    }
}

__global__ __launch_bounds__(512, 4) void bpnet_fused(
    const float* __restrict__ nodes,      // [N, 13]
    const int*   __restrict__ edges,      // [E, 3]
    const int*   __restrict__ edge_types, // [E, 3]
    const uint*  __restrict__ tab,        // packed tables (TAB_N dwords)
    float*       __restrict__ out)        // [N, 13] (pre-zeroed)
{
    __shared__ __align__(16) uint sh[SH_N];
    const int tid  = threadIdx.x;
    const int lane = tid & 63;
    const int wv   = tid >> 6;        // 0..7
    const int e4   = lane >> 4;       // edge within wave's 4
    const int g    = lane & 15;       // rank octet 8g..8g+7
    const int eb   = (blockIdx.x * 8 + wv) * 4;

    // ---- wave metadata (issued first: longest dependent chain) ----
    int ev = 0, tv = 0;
    if (lane < 12) {
        ev = edges[eb * OD + lane];
        tv = edge_types[eb * OD + lane];
    }

    // ---- gather 12 node rows as packed h2 d-pairs into per-wave LDS ----
    // (region disjoint from staged tables; overlaps the table copy below)
    uint* mynr = sh + NROW_OFF + wv * 96;
#pragma unroll
    for (int pass = 0; pass < 2; ++pass) {
        const int idx = pass * 64 + lane;
        if (idx < 96) {
            const int r = idx >> 3, p = idx & 7;
            const int nr_ = __shfl(ev, r, 64);
            uint v = 0;
            if (p < 6)       v = pk(nodes[(size_t)nr_ * DD + 2 * p],
                                    nodes[(size_t)nr_ * DD + 2 * p + 1]);
            else if (p == 6) v = pk(nodes[(size_t)nr_ * DD + 12], 0.f);
            mynr[r * 8 + p] = v;
        }
    }

    // ---- stage packed tables into LDS (flat uint4 copy) ----
    for (int k4 = tid; k4 < TAB_N / 4; k4 += 512)
        ((uint4*)sh)[k4] = ((const uint4*)tab)[k4];
    __syncthreads();

    int tg[OD], et[OD];
#pragma unroll
    for (int i = 0; i < OD; ++i) {
        tg[i] = __shfl(ev, e4 * OD + i, 64);
        et[i] = __shfl(tv, e4 * OD + i, 64);
    }

    // ---- stage 1: t[o][0..7] for ranks 8g..8g+7 of edge e4 ----
    float t[OD][8];
#pragma unroll
    for (int o = 0; o < OD; ++o) {
        const uint* nh = mynr + (e4 * OD + o) * 8;
        const uint4 n0 = *(const uint4*)(nh);       // d-pairs 0..3 (broadcast)
        const uint4 n1 = *(const uint4*)(nh + 4);   // d-pairs 4..6 (+pad)
        const float4 b0 = *(const float4*)((const float*)(sh + B1A_OFF) + et[o] * 64 + 4 * g);
        const float4 b1 = *(const float4*)((const float*)(sh + B1B_OFF) + et[o] * 64 + 4 * g);
        float s[8] = {b0.x, b0.y, b0.z, b0.w, b1.x, b1.y, b1.z, b1.w};
        const uint* wa = sh + W1A_OFF + (et[o] * 7) * 64 + 4 * g;
        const uint* wb = sh + W1B_OFF + (et[o] * 7) * 64 + 4 * g;
#define S1(p, nv) { const uint4 wA = *(const uint4*)(wa + (p) * 64);          \
                    const uint4 wB = *(const uint4*)(wb + (p) * 64);          \
            const h2 nn = ash2(nv);                                           \
            s[0] = __builtin_amdgcn_fdot2(nn, ash2(wA.x), s[0], false);       \
            s[1] = __builtin_amdgcn_fdot2(nn, ash2(wA.y), s[1], false);       \
            s[2] = __builtin_amdgcn_fdot2(nn, ash2(wA.z), s[2], false);       \
            s[3] = __builtin_amdgcn_fdot2(nn, ash2(wA.w), s[3], false);       \
            s[4] = __builtin_amdgcn_fdot2(nn, ash2(wB.x), s[4], false);       \
            s[5] = __builtin_amdgcn_fdot2(nn, ash2(wB.y), s[5], false);       \
            s[6] = __builtin_amdgcn_fdot2(nn, ash2(wB.z), s[6], false);       \
            s[7] = __builtin_amdgcn_fdot2(nn, ash2(wB.w), s[7], false); }
        S1(0, n0.x) S1(1, n0.y) S1(2, n0.z) S1(3, n0.w)
        S1(4, n1.x) S1(5, n1.y) S1(6, n1.z)
#undef S1
#pragma unroll
        for (int r = 0; r < 8; ++r) t[o][r] = fmaxf(s[r], 0.f);
    }

    // ---- stage 2: facts in registers -> h2, dot2 vs W2H rows ----
#pragma unroll
    for (int i = 0; i < OD; ++i) {
        const int j = (i + 1) % OD, k = (i + 2) % OD;
        uint fh[4];
#pragma unroll
        for (int r = 0; r < 4; ++r)
            fh[r] = pk(t[j][2 * r] * t[k][2 * r], t[j][2 * r + 1] * t[k][2 * r + 1]);
        const int it = i * NP + et[i];
        const uint* wb2 = sh + W2H_OFF + (it * DD) * 64 + 4 * g;
        float c[DD];
#pragma unroll
        for (int dd = 0; dd < DD; ++dd) {
            const uint4 w = *(const uint4*)(wb2 + dd * 64);
            float a = __builtin_amdgcn_fdot2(ash2(fh[0]), ash2(w.x), 0.f, false);
            a = __builtin_amdgcn_fdot2(ash2(fh[1]), ash2(w.y), a, false);
            a = __builtin_amdgcn_fdot2(ash2(fh[2]), ash2(w.z), a, false);
            a = __builtin_amdgcn_fdot2(ash2(fh[3]), ash2(w.w), a, false);
            c[dd] = a;
        }
#pragma unroll
        for (int dd = 0; dd < DD; ++dd) c[dd] = row_sum16(c[dd]);
        float q = c[0];
#pragma unroll
        for (int dd = 1; dd < DD; ++dd) q = (g == dd) ? c[dd] : q;
        q += ((const float*)(sh + HOB_OFF))[it * 16 + g];
        if (g < DD) atomicAdd(out + (size_t)tg[i] * DD + g, q);
    }
}

extern "C" void kernel_launch(void* const* d_in, const int* in_sizes, int n_in,
                              void* d_out, int out_size, void* d_ws, size_t ws_size,
                              hipStream_t stream) {
    const float* nodes      = (const float*)d_in[0];
    const float* bp_params  = (const float*)d_in[1];
    const float* bp_bias    = (const float*)d_in[2];
    const float* ho_params  = (const float*)d_in[3];
    const float* ho_bias    = (const float*)d_in[4];
    const int*   edges      = (const int*)d_in[5];
    const int*   edge_types = (const int*)d_in[6];
    float* out = (float*)d_out;
    uint*  ws  = (uint*)d_ws;

    const int E = in_sizes[5] / OD;   // 16384

    // pack kernel also zeroes out (poisoned 0xAA before every timed call)
    bpnet_pack<<<(TAB_N + 255) / 256, 256, 0, stream>>>(
        bp_params, bp_bias, ho_params, ho_bias, ws, (uint*)out, out_size);

    // E/32 = 512 blocks x 8 waves x 4 edges = 16384
    bpnet_fused<<<E / 32, 512, 0, stream>>>(nodes, edges, edge_types, ws, out);
}